// Round 3
// baseline (15892.940 us; speedup 1.0000x reference)
//
#include <hip/hip_runtime.h>
#include <cstdint>
#include <cstddef>
#include <math.h>

#define B_   32
#define S_   2048
#define IN_  128
#define H_   256
#define Q_   16
#define M_   64
#define D_   4      // layer-1 lag (LDS a-ring depth 8 > D+1)

typedef unsigned long long u64;

__device__ __forceinline__ float4 ld4(const float* p) { return *(const float4*)p; }

#define AGLD64(p)    __hip_atomic_load((p),  __ATOMIC_RELAXED, __HIP_MEMORY_SCOPE_AGENT)
#define AGST64(p, v) __hip_atomic_store((p), (v), __ATOMIC_RELAXED, __HIP_MEMORY_SCOPE_AGENT)

// fast sigmoid / tanh: exact identities on __expf (v_exp_f32), ~1e-7 abs err
__device__ __forceinline__ float sigm_f(float x) { return 1.0f / (1.0f + __expf(-x)); }
__device__ __forceinline__ float tanh_f(float x) { return 1.0f - 2.0f / (__expf(2.0f * x) + 1.0f); }

// ---------------------------------------------------------------------------
// Fused 2-layer LSTM recurrence. 256 blocks = 32 rows x 8; 1 block/CU.
// Mapping n=f>>5, b=f&31 puts a row's 8 blocks on ONE XCD under round-robin
// dispatch (f%8 == b%8) -> the L2 fast path below usually hits.
// Block owns 32 hidden cols of EACH layer (all 4 gates per col).
// Lane layout: (wave w, col-group rg=l>>3, k-chunk kc=l&7). Each lane owns
// ONE column x 4 gates and a 32-elem k-chunk; dots are k-parallel
// (conflict-free b128 LDS reads + 3-level shfl_xor butterfly); gate
// combine/cell/act/publish fully in-lane.
// Exchange, per element: u64 = (tag<<32)|fp32bits, published TWICE:
//   fast: plain volatile store  -> stays in XCD L2 (visible same-XCD ~200cy)
//   slow: agent-scope atomic    -> coherent everywhere (proven protocol)
// Consumers poll fast copy (bounded 6 spins, issued before the shadow work)
// then fall back to the slow copy. Stale tags make wrong-placement inert ->
// correctness never depends on XCD assignment (G16); placement only = speed.
// All-fp32 arithmetic (bf16 anywhere shifts kNN top-3 picks -> 0.46 absmax).
// ---------------------------------------------------------------------------
__global__ __launch_bounds__(256, 1) void lstm2(
    const float* __restrict__ x,     // [B,S,128]
    const float* __restrict__ Wih0, const float* __restrict__ bih0,
    const float* __restrict__ bhh0, const float* __restrict__ Whh0,
    const float* __restrict__ Wih1, const float* __restrict__ bih1,
    const float* __restrict__ bhh1, const float* __restrict__ Whh1,
    float* __restrict__ out,         // [B,S,256]  (= d_out, layer-1 hidden)
    u64* __restrict__ exs,           // slow region [32][2mat][2par][256] u64
    u64* __restrict__ exf)           // fast region, same shape
{
  const int f = blockIdx.x;
  const int n = f >> 5;                    // block-in-row 0..7
  const int b = f & 31;                    // row 0..31  (f%8 == b%8 -> XCD)

  const int tid = threadIdx.x;
  const int w   = tid >> 6;                // wave 0..3
  const int l   = tid & 63;
  const int kc  = l & 7;                   // k-chunk lane 0..7
  const int rg  = l >> 3;                  // col-in-wave 0..7
  const int wrg = w * 8 + rg;              // col-in-block 0..31
  const int col = n * 32 + wrg;            // global hidden col 0..255

  __shared__ float w1[128][257];           // Wih1 block slice, padded rows
  __shared__ float aring[8][256];          // last 8 layer-0 hidden vectors
  __shared__ float hring[2][256];          // layer-1 hidden, parity dbuf
  __shared__ float x_sh[2][IN_];

#pragma unroll
  for (int s2 = 0; s2 < 8; s2++) aring[s2][tid] = 0.0f;
  hring[0][tid] = 0.0f;
  hring[1][tid] = 0.0f;

  // --- register weights, chunk layout k = 4*kc + 32*j + i ---------------
  float4 wf0[4][8], wf1[4][8], wi0[4][4];
  float rb0[4], rb1[4];
#pragma unroll
  for (int g = 0; g < 4; g++) {
    const int row = g * 256 + col;
    const float* p0 = Whh0 + (size_t)row * 256 + 4 * kc;
    const float* p1 = Whh1 + (size_t)row * 256 + 4 * kc;
    const float* pi = Wih0 + (size_t)row * 128 + 4 * kc;
#pragma unroll
    for (int j = 0; j < 8; j++) {
      wf0[g][j] = ld4(p0 + 32 * j);
      wf1[g][j] = ld4(p1 + 32 * j);
    }
#pragma unroll
    for (int j = 0; j < 4; j++) wi0[g][j] = ld4(pi + 32 * j);
    rb0[g] = bih0[row] + bhh0[row];
    rb1[g] = bih1[row] + bhh1[row];
    // stage this lane's Wih1 chunk into w1[g*32+wrg][4*kc + 32*j .. +3]
    const float* pw = Wih1 + (size_t)row * 256 + 4 * kc;
    float* dst = &w1[g * 32 + wrg][4 * kc];
#pragma unroll
    for (int j = 0; j < 8; j++) *(float4*)(dst + 32 * j) = ld4(pw + 32 * j);
  }

  const float* xrow = x + (size_t)b * S_ * IN_;
  float* outp = out + (size_t)b * S_ * H_;
  u64* sexb = exs + (size_t)b * 1024;                       // [2mat][2par][256]
  volatile u64* fexb = (volatile u64*)(exf + (size_t)b * 1024);
  // idx(mat,par,e) = ((mat*2+par)<<8) + e

  if (tid < IN_) {
    x_sh[0][tid] = xrow[tid];
    x_sh[1][tid] = xrow[IN_ + tid];
  }
  float xreg = (tid < IN_) ? xrow[(size_t)2 * IN_ + tid] : 0.0f;
  float cst0 = 0.0f, cst1 = 0.0f;          // cell states (replicated / kc)
  float xa0s[4], xa1s[4] = {0, 0, 0, 0};
  __syncthreads();

  // xa0 for t=0
  {
    const float* xb = x_sh[0];
    float4 xv[4];
#pragma unroll
    for (int j = 0; j < 4; j++) xv[j] = ld4(xb + 4 * kc + 32 * j);
#pragma unroll
    for (int g = 0; g < 4; g++) {
      float4 s4 = {0, 0, 0, 0};
#pragma unroll
      for (int j = 0; j < 4; j++) {
        s4.x += wi0[g][j].x * xv[j].x; s4.y += wi0[g][j].y * xv[j].y;
        s4.z += wi0[g][j].z * xv[j].z; s4.w += wi0[g][j].w * xv[j].w;
      }
      float s = (s4.x + s4.y) + (s4.z + s4.w);
      s += __shfl_xor(s, 1); s += __shfl_xor(s, 2); s += __shfl_xor(s, 4);
      xa0s[g] = s + rb0[g];
    }
  }

  const bool own = ((tid >> 5) == n);      // gather element tid is own-block
  bool dead = false;
  for (int t = 0; t < S_ + D_; ++t) {
    const bool doA = (t < S_);
    const int  u   = t - D_;
    const bool doH = (u >= 0);
    const int  pa = t & 1, ph = u & 1;

    // ---- 1. k-parallel gate dots + in-lane cells + early publish -------
    if (doA) {
      const float* ap = aring[(t - 1) & 7];
      float4 av[8];
#pragma unroll
      for (int j = 0; j < 8; j++) av[j] = ld4(ap + 4 * kc + 32 * j);
      float gv[4];
#pragma unroll
      for (int g = 0; g < 4; g++) {
        float4 s4 = {0, 0, 0, 0};
#pragma unroll
        for (int j = 0; j < 8; j++) {
          s4.x += wf0[g][j].x * av[j].x; s4.y += wf0[g][j].y * av[j].y;
          s4.z += wf0[g][j].z * av[j].z; s4.w += wf0[g][j].w * av[j].w;
        }
        float s = (s4.x + s4.y) + (s4.z + s4.w);
        s += __shfl_xor(s, 1); s += __shfl_xor(s, 2); s += __shfl_xor(s, 4);
        gv[g] = s + xa0s[g];
      }
      float ig = sigm_f(gv[0]);
      float fg = sigm_f(gv[1]);
      float cg = tanh_f(gv[2]);
      float og = sigm_f(gv[3]);
      cst0 = fg * cst0 + ig * cg;
      float a = og * tanh_f(cst0);
      if (kc == 0) {                       // 8 lanes/wave publish own cols
        u64 pk = ((u64)(unsigned)(t + 1) << 32) | (u64)__float_as_uint(a);
        fexb[((0 * 2 + pa) << 8) + col] = pk;            // L2 fast path
        AGST64(sexb + ((0 * 2 + pa) << 8) + col, pk);    // coherent path
        aring[t & 7][col] = a;                           // own cols local
      }
    }
    if (doH) {
      const float* hp = hring[(t - 1) & 1];
      float4 hv[8];
#pragma unroll
      for (int j = 0; j < 8; j++) hv[j] = ld4(hp + 4 * kc + 32 * j);
      float gv[4];
#pragma unroll
      for (int g = 0; g < 4; g++) {
        float4 s4 = {0, 0, 0, 0};
#pragma unroll
        for (int j = 0; j < 8; j++) {
          s4.x += wf1[g][j].x * hv[j].x; s4.y += wf1[g][j].y * hv[j].y;
          s4.z += wf1[g][j].z * hv[j].z; s4.w += wf1[g][j].w * hv[j].w;
        }
        float s = (s4.x + s4.y) + (s4.z + s4.w);
        s += __shfl_xor(s, 1); s += __shfl_xor(s, 2); s += __shfl_xor(s, 4);
        gv[g] = s + xa1s[g];
      }
      float ig = sigm_f(gv[0]);
      float fg = sigm_f(gv[1]);
      float cg = tanh_f(gv[2]);
      float og = sigm_f(gv[3]);
      cst1 = fg * cst1 + ig * cg;
      float h = og * tanh_f(cst1);
      if (kc == 0) {
        outp[(size_t)u * H_ + col] = h;    // plain store for epilogue
        u64 pk = ((u64)(unsigned)(u + 1) << 32) | (u64)__float_as_uint(h);
        fexb[((1 * 2 + ph) << 8) + col] = pk;
        AGST64(sexb + ((1 * 2 + ph) << 8) + col, pk);
        hring[u & 1][col] = h;
      }
    }

    // ---- 2. issue fast-path gather loads (fly during shadow work) ------
    bool needA = doA && !own && !dead;
    bool needH = doH && !own && !dead;
    const unsigned eA = (unsigned)(t + 1), eH = (unsigned)(u + 1);
    volatile u64* fA = fexb + ((0 * 2 + pa) << 8) + tid;
    volatile u64* fH = fexb + ((1 * 2 + ph) << 8) + tid;
    u64 vA = 0, vH = 0;
    if (needA) vA = *fA;
    if (needH) vH = *fH;

    // ---- 3. off-critical-path work (overlaps exchange latency) ---------
    // 3a. next xa0 from x_sh
    if (t + 1 < S_) {
      const float* xb = x_sh[(t + 1) & 1];
      float4 xv[4];
#pragma unroll
      for (int j = 0; j < 4; j++) xv[j] = ld4(xb + 4 * kc + 32 * j);
#pragma unroll
      for (int g = 0; g < 4; g++) {
        float4 s4 = {0, 0, 0, 0};
#pragma unroll
        for (int j = 0; j < 4; j++) {
          s4.x += wi0[g][j].x * xv[j].x; s4.y += wi0[g][j].y * xv[j].y;
          s4.z += wi0[g][j].z * xv[j].z; s4.w += wi0[g][j].w * xv[j].w;
        }
        float s = (s4.x + s4.y) + (s4.z + s4.w);
        s += __shfl_xor(s, 1); s += __shfl_xor(s, 2); s += __shfl_xor(s, 4);
        xa0s[g] = s + rb0[g];
      }
    }
    // 3b. xa1 for layer-1 step v = u+1: w1 (padded b128 stream) x aring[v]
    {
      const int v = t - D_ + 1;
      if (v >= 0 && v < S_) {
        const float* avp = aring[v & 7];
        float4 av[8];
#pragma unroll
        for (int j = 0; j < 8; j++) av[j] = ld4(avp + 4 * kc + 32 * j);
#pragma unroll
        for (int g = 0; g < 4; g++) {
          const float* wr = &w1[g * 32 + wrg][4 * kc];
          float4 s4 = {0, 0, 0, 0};
#pragma unroll
          for (int j = 0; j < 8; j++) {
            float4 wv = ld4(wr + 32 * j);
            s4.x += wv.x * av[j].x; s4.y += wv.y * av[j].y;
            s4.z += wv.z * av[j].z; s4.w += wv.w * av[j].w;
          }
          float s = (s4.x + s4.y) + (s4.z + s4.w);
          s += __shfl_xor(s, 1); s += __shfl_xor(s, 2); s += __shfl_xor(s, 4);
          xa1s[g] = s + rb1[g];
        }
      }
    }
    // 3c. x prefetch
    float xreg_n = 0.0f;
    if (tid < IN_ && t + 2 < S_) {
      int tn = (t + 3 < S_) ? t + 3 : S_ - 1;
      xreg_n = xrow[(size_t)tn * IN_ + tid];
    }

    // ---- 4. check fast path; bounded spin; coherent fallback -----------
    if (needA && (unsigned)(vA >> 32) == eA) needA = false;
    if (needH && (unsigned)(vH >> 32) == eH) needH = false;
#pragma unroll 1
    for (int spin = 0; (needA || needH) && spin < 6; ++spin) {
      if (needA) { vA = *fA; if ((unsigned)(vA >> 32) == eA) needA = false; }
      if (needH) { vH = *fH; if ((unsigned)(vH >> 32) == eH) needH = false; }
    }
    if (needA || needH) {                  // slow coherent fallback
      u64* sA = sexb + ((0 * 2 + pa) << 8) + tid;
      u64* sH = sexb + ((1 * 2 + ph) << 8) + tid;
      unsigned guard = 0;
      while (needA || needH) {
        if (needA) { vA = AGLD64(sA); if ((unsigned)(vA >> 32) == eA) needA = false; }
        if (needH) { vH = AGLD64(sH); if ((unsigned)(vH >> 32) == eH) needH = false; }
        if (++guard >= (1u << 20)) { dead = true; break; }
      }
    }
    if (doA && !own) aring[t & 7][tid] = __uint_as_float((unsigned)vA);
    if (doH && !own) hring[u & 1][tid] = __uint_as_float((unsigned)vH);

    if (tid < IN_ && t < S_) x_sh[t & 1][tid] = xreg;
    xreg = xreg_n;
    __syncthreads();
  }
}

// ---------------------------------------------------------------------------
// kNN memory read. One wave per token. enh = qw * enhanced  [MT,256] fp32.
// ---------------------------------------------------------------------------
__global__ __launch_bounds__(256) void knn_enh(
    const float* __restrict__ lstm, const float* __restrict__ Wcq,
    const float* __restrict__ bcq, const float* __restrict__ keys,
    const float* __restrict__ vals, const float* __restrict__ qwp,
    float* __restrict__ enh)
{
  const int tid  = threadIdx.x;
  const int wave = tid >> 6, lane = tid & 63;
  const int t = blockIdx.x * 4 + wave;

  __shared__ float xsh[4][256];
  __shared__ float qsh[4][16];

  const float* xrow = lstm + (size_t)t * H_;
  float4 x4 = ld4(xrow + lane * 4);
  *(float4*)&xsh[wave][lane * 4] = x4;
  __syncthreads();

  const int j = lane & 15, seg = lane >> 4;
  const float* wrow = Wcq + j * H_ + seg * 64;
  const float* xseg = &xsh[wave][seg * 64];
  float p = 0.0f;
#pragma unroll
  for (int c = 0; c < 64; c += 4) {
    float4 w4 = ld4(wrow + c);
    p += w4.x * xseg[c] + w4.y * xseg[c + 1] + w4.z * xseg[c + 2] + w4.w * xseg[c + 3];
  }
  p += __shfl_xor(p, 16);
  p += __shfl_xor(p, 32);
  float q = tanhf(p + bcq[j]);

  float sq = q * q;
  sq += __shfl_xor(sq, 1); sq += __shfl_xor(sq, 2);
  sq += __shfl_xor(sq, 4); sq += __shfl_xor(sq, 8);
  float qn = q / (sqrtf(sq) + 1e-8f);
  if (lane < 16) qsh[wave][lane] = qn;
  __syncthreads();

  const int m = lane;
  const float* krow = keys + m * Q_;
  float kv[16]; float kn2 = 0.0f;
#pragma unroll
  for (int jj = 0; jj < 16; jj++) { kv[jj] = krow[jj]; kn2 += kv[jj] * kv[jj]; }
  float rn = 1.0f / (sqrtf(kn2) + 1e-8f);
  float sim = 0.0f;
#pragma unroll
  for (int jj = 0; jj < 16; jj++) sim += qsh[wave][jj] * kv[jj];
  sim *= rn;

  float rem = sim;
  float tv[3]; int ti[3];
#pragma unroll
  for (int k = 0; k < 3; k++) {
    float v = rem; int idx = m;
#pragma unroll
    for (int d = 1; d < 64; d <<= 1) {
      float ov = __shfl_xor(v, d);
      int   oi = __shfl_xor(idx, d);
      if (ov > v || (ov == v && oi < idx)) { v = ov; idx = oi; }
    }
    tv[k] = v; ti[k] = idx;
    if (m == idx) rem = -INFINITY;
  }
  float tot = tv[0] + tv[1] + tv[2];

  float ex = 0, ey = 0, ez = 0, ew = 0;
#pragma unroll
  for (int k = 0; k < 3; k++) {
    float4 vv = ld4(vals + (size_t)ti[k] * H_ + lane * 4);
    ex += tv[k] * vv.x; ey += tv[k] * vv.y;
    ez += tv[k] * vv.z; ew += tv[k] * vv.w;
  }
  float inv = (tot > 0.0f) ? 1.0f / tot : 0.0f;
  const float qw = qwp[0];

  float4 o;
  o.x = qw * ex * inv; o.y = qw * ey * inv;
  o.z = qw * ez * inv; o.w = qw * ew * inv;
  *(float4*)&enh[(size_t)t * H_ + lane * 4] = o;
}

// ---------------------------------------------------------------------------
// Final projection, IN-PLACE on io (= d_out). Block owns 64 rows x all 256
// cols; reads its own rows, writes after the K-loop -> race-free in-place.
// ---------------------------------------------------------------------------
__global__ __launch_bounds__(256) void gemm_cat(
    float* __restrict__ io, const float* __restrict__ A2,
    const float* __restrict__ Bw, const float* __restrict__ bias,
    const float* __restrict__ cwp)
{
  __shared__ float As[16][68];
  __shared__ float Bs[16][260];
  const int tid  = threadIdx.x;
  const int row0 = blockIdx.x * 64;
  const int tx = tid & 15, ty = tid >> 4;
  const int lr = tid >> 2;
  const int lk = (tid & 3) << 2;
  const float cw = cwp[0];

  float acc[4][16];
#pragma unroll
  for (int i = 0; i < 4; i++)
#pragma unroll
    for (int j = 0; j < 16; j++) acc[i][j] = 0.0f;

  for (int k0 = 0; k0 < 512; k0 += 16) {
    float4 av;
    if (k0 < 256) {
      av = ld4(io + (size_t)(row0 + lr) * 256 + k0 + lk);
      av.x *= cw; av.y *= cw; av.z *= cw; av.w *= cw;
    } else {
      av = ld4(A2 + (size_t)(row0 + lr) * 256 + (k0 - 256) + lk);
    }
    As[lk + 0][lr] = av.x; As[lk + 1][lr] = av.y;
    As[lk + 2][lr] = av.z; As[lk + 3][lr] = av.w;
    const float* bp = Bw + (size_t)tid * 512 + k0;
#pragma unroll
    for (int q = 0; q < 4; q++) {
      float4 b4 = ld4(bp + 4 * q);
      Bs[4 * q + 0][tid] = b4.x; Bs[4 * q + 1][tid] = b4.y;
      Bs[4 * q + 2][tid] = b4.z; Bs[4 * q + 3][tid] = b4.w;
    }
    __syncthreads();
#pragma unroll
    for (int k = 0; k < 16; k++) {
      float4 a4 = *(const float4*)&As[k][ty << 2];
      float aa[4] = {a4.x, a4.y, a4.z, a4.w};
#pragma unroll
      for (int cc = 0; cc < 4; cc++) {
        float4 b4 = *(const float4*)&Bs[k][cc * 64 + (tx << 2)];
        float bb[4] = {b4.x, b4.y, b4.z, b4.w};
#pragma unroll
        for (int i = 0; i < 4; i++)
#pragma unroll
          for (int jj = 0; jj < 4; jj++) acc[i][cc * 4 + jj] += aa[i] * bb[jj];
      }
    }
    __syncthreads();
  }

#pragma unroll
  for (int i = 0; i < 4; i++) {
#pragma unroll
    for (int cc = 0; cc < 4; cc++) {
      int c0 = cc * 64 + (tx << 2);
      float4 o;
      o.x = acc[i][cc * 4 + 0] + bias[c0 + 0];
      o.y = acc[i][cc * 4 + 1] + bias[c0 + 1];
      o.z = acc[i][cc * 4 + 2] + bias[c0 + 2];
      o.w = acc[i][cc * 4 + 3] + bias[c0 + 3];
      *(float4*)&io[(size_t)(row0 + (ty << 2) + i) * 256 + c0] = o;
    }
  }
}

// ---------------------------------------------------------------------------
extern "C" void kernel_launch(void* const* d_in, const int* in_sizes, int n_in,
                              void* d_out, int out_size, void* d_ws, size_t ws_size,
                              hipStream_t stream)
{
  const float* x    = (const float*)d_in[0];
  const float* Wih0 = (const float*)d_in[1];
  const float* Whh0 = (const float*)d_in[2];
  const float* bih0 = (const float*)d_in[3];
  const float* bhh0 = (const float*)d_in[4];
  const float* Wih1 = (const float*)d_in[5];
  const float* Whh1 = (const float*)d_in[6];
  const float* bih1 = (const float*)d_in[7];
  const float* bhh1 = (const float*)d_in[8];
  const float* Wcq  = (const float*)d_in[9];
  const float* bcq  = (const float*)d_in[10];
  const float* keys = (const float*)d_in[11];
  const float* vals = (const float*)d_in[12];
  const float* Wout = (const float*)d_in[13];
  const float* bout = (const float*)d_in[14];
  const float* cw   = (const float*)d_in[15];
  const float* qw   = (const float*)d_in[16];
  float* out = (float*)d_out;

  // ws: [slow ex 256KB][fast ex 256KB] (dead after lstm2), overlapped with
  // enh [MT,256] f32 for the epilogue kernels.
  const size_t HE = (size_t)B_ * S_ * H_;
  if (ws_size < HE * sizeof(float)) return;   // 67.1 MB (round-4 proven OK)
  u64* exs = (u64*)d_ws;
  u64* exf = exs + (size_t)32 * 1024;
  float* enh = (float*)d_ws;

  const int MT = B_ * S_;
  dim3 blk(256);

  hipMemsetAsync(exs, 0, (size_t)2 * 32 * 1024 * sizeof(u64), stream);
  lstm2<<<dim3(256), blk, 0, stream>>>(x, Wih0, bih0, bhh0, Whh0,
                                       Wih1, bih1, bhh1, Whh1, out, exs, exf);

  knn_enh<<<dim3(MT / 4), blk, 0, stream>>>(out, Wcq, bcq, keys, vals, qw, enh);

  gemm_cat<<<dim3(MT / 64), blk, 0, stream>>>(out, enh, Wout, bout, cw);
}

// Round 5
// 13568.964 us; speedup vs baseline: 1.1713x; 1.1713x over previous
//
#include <hip/hip_runtime.h>
#include <cstdint>
#include <cstddef>
#include <math.h>

#define B_   32
#define S_   2048
#define IN_  128
#define H_   256
#define Q_   16
#define M_   64
#define D_   4      // layer-1 lag (LDS a-ring depth 8 > D+1)

typedef unsigned long long u64;
typedef __attribute__((ext_vector_type(4))) unsigned int u32x4;

__device__ __forceinline__ float4 ld4(const float* p) { return *(const float4*)p; }

#define AGLD64(p)    __hip_atomic_load((p),  __ATOMIC_RELAXED, __HIP_MEMORY_SCOPE_AGENT)
#define AGST64(p, v) __hip_atomic_store((p), (v), __ATOMIC_RELAXED, __HIP_MEMORY_SCOPE_AGENT)

// Coalesced poll of TWO tagged u64 elements (16B, aligned). sc0 sc1 bypass
// L1/L2 so the load observes the MALL (the agent-atomic coherence point),
// but as a NORMAL load it wave-coalesces into line requests instead of 64
// serialized atomic transactions. Tags self-validate; no atomicity needed
// (each element's 8B was written by one atomic store -> no tearing).
__device__ __forceinline__ u32x4 mall_load_2x64(const u64* p) {
  u32x4 q;
  asm volatile("global_load_dwordx4 %0, %1, off sc0 sc1\n\ts_waitcnt vmcnt(0)"
               : "=v"(q) : "v"(p) : "memory");
  return q;
}

// fast sigmoid / tanh: exact identities on __expf (v_exp_f32), ~1e-7 abs err
__device__ __forceinline__ float sigm_f(float x) { return 1.0f / (1.0f + __expf(-x)); }
__device__ __forceinline__ float tanh_f(float x) { return 1.0f - 2.0f / (__expf(2.0f * x) + 1.0f); }

// ---------------------------------------------------------------------------
// Fused 2-layer LSTM recurrence. 256 blocks = 32 rows x 8; 1 block/CU.
// Block owns 32 hidden cols of EACH layer (all 4 gates per col).
// Lane layout: (wave w, col-group rg=l>>3, k-chunk kc=l&7). Each lane owns
// ONE column x 4 gates and a 32-elem k-chunk; dots are k-parallel
// (conflict-free b128 LDS reads + 3-level shfl_xor butterfly); gate
// combine/cell/act/publish fully in-lane.
// Exchange: u64 = (tag<<32)|fp32bits per element, parity-2 ring, published
// via agent-scope relaxed atomic stores (proven protocol, rounds 2-3).
// GATHER is the hot path: lanes 0..127 poll A-plane PAIRS, lanes 128..255
// poll H-plane PAIRS with coalesced sc0+sc1 dwordx4 loads (16 tries), then
// fall back to the proven per-element agent-atomic loop. Round-4's L2
// "fast path" is REMOVED: plain-store visibility probes are unsound
// (L2 eviction makes them false-positive across XCDs).
// All-fp32 arithmetic (bf16 anywhere shifts kNN top-3 picks -> 0.46 absmax).
// ---------------------------------------------------------------------------
__global__ __launch_bounds__(256, 1) void lstm2(
    const float* __restrict__ x,     // [B,S,128]
    const float* __restrict__ Wih0, const float* __restrict__ bih0,
    const float* __restrict__ bhh0, const float* __restrict__ Whh0,
    const float* __restrict__ Wih1, const float* __restrict__ bih1,
    const float* __restrict__ bhh1, const float* __restrict__ Whh1,
    float* __restrict__ out,         // [B,S,256]  (= d_out, layer-1 hidden)
    u64* __restrict__ exs)           // [32][2mat][2par][256] tagged u64
{
  const int f = blockIdx.x;
  const int n = f >> 5;                    // block-in-row 0..7
  const int b = f & 31;                    // row 0..31

  const int tid = threadIdx.x;
  const int w   = tid >> 6;                // wave 0..3
  const int l   = tid & 63;
  const int kc  = l & 7;                   // k-chunk lane 0..7
  const int rg  = l >> 3;                  // col-in-wave 0..7
  const int wrg = w * 8 + rg;              // col-in-block 0..31
  const int col = n * 32 + wrg;            // global hidden col 0..255

  __shared__ float w1[128][257];           // Wih1 block slice, padded rows
  __shared__ float aring[8][256];          // last 8 layer-0 hidden vectors
  __shared__ float hring[2][256];          // layer-1 hidden, parity dbuf
  __shared__ float x_sh[2][IN_];

#pragma unroll
  for (int s2 = 0; s2 < 8; s2++) aring[s2][tid] = 0.0f;
  hring[0][tid] = 0.0f;
  hring[1][tid] = 0.0f;

  // --- register weights, chunk layout k = 4*kc + 32*j + i ---------------
  float4 wf0[4][8], wf1[4][8], wi0[4][4];
  float rb0[4], rb1[4];
#pragma unroll
  for (int g = 0; g < 4; g++) {
    const int row = g * 256 + col;
    const float* p0 = Whh0 + (size_t)row * 256 + 4 * kc;
    const float* p1 = Whh1 + (size_t)row * 256 + 4 * kc;
    const float* pi = Wih0 + (size_t)row * 128 + 4 * kc;
#pragma unroll
    for (int j = 0; j < 8; j++) {
      wf0[g][j] = ld4(p0 + 32 * j);
      wf1[g][j] = ld4(p1 + 32 * j);
    }
#pragma unroll
    for (int j = 0; j < 4; j++) wi0[g][j] = ld4(pi + 32 * j);
    rb0[g] = bih0[row] + bhh0[row];
    rb1[g] = bih1[row] + bhh1[row];
    // stage this lane's Wih1 chunk into w1[g*32+wrg][4*kc + 32*j .. +3]
    const float* pw = Wih1 + (size_t)row * 256 + 4 * kc;
    float* dst = &w1[g * 32 + wrg][4 * kc];
#pragma unroll
    for (int j = 0; j < 8; j++) *(float4*)(dst + 32 * j) = ld4(pw + 32 * j);
  }

  const float* xrow = x + (size_t)b * S_ * IN_;
  float* outp = out + (size_t)b * S_ * H_;
  u64* sexb = exs + (size_t)b * 1024;      // [2mat][2par][256]
  // idx(mat,par,e) = ((mat*2+par)<<8) + e

  if (tid < IN_) {
    x_sh[0][tid] = xrow[tid];
    x_sh[1][tid] = xrow[IN_ + tid];
  }
  float xreg = (tid < IN_) ? xrow[(size_t)2 * IN_ + tid] : 0.0f;
  float cst0 = 0.0f, cst1 = 0.0f;          // cell states (replicated / kc)
  float xa0s[4], xa1s[4] = {0, 0, 0, 0};
  __syncthreads();

  // xa0 for t=0
  {
    const float* xb = x_sh[0];
    float4 xv[4];
#pragma unroll
    for (int j = 0; j < 4; j++) xv[j] = ld4(xb + 4 * kc + 32 * j);
#pragma unroll
    for (int g = 0; g < 4; g++) {
      float4 s4 = {0, 0, 0, 0};
#pragma unroll
      for (int j = 0; j < 4; j++) {
        s4.x += wi0[g][j].x * xv[j].x; s4.y += wi0[g][j].y * xv[j].y;
        s4.z += wi0[g][j].z * xv[j].z; s4.w += wi0[g][j].w * xv[j].w;
      }
      float s = (s4.x + s4.y) + (s4.z + s4.w);
      s += __shfl_xor(s, 1); s += __shfl_xor(s, 2); s += __shfl_xor(s, 4);
      xa0s[g] = s + rb0[g];
    }
  }

  bool dead = false;
  for (int t = 0; t < S_ + D_; ++t) {
    const bool doA = (t < S_);
    const int  u   = t - D_;
    const bool doH = (u >= 0);
    const int  pa = t & 1, ph = u & 1;
    const unsigned eA = (unsigned)(t + 1), eH = (unsigned)(u + 1);

    // ---- 0. x prefetch issued FIRST (HBM latency drains under the dots) --
    float xreg_n = 0.0f;
    if (tid < IN_ && t + 2 < S_) {
      int tn = (t + 3 < S_) ? t + 3 : S_ - 1;
      xreg_n = xrow[(size_t)tn * IN_ + tid];
    }

    // ---- 1. k-parallel gate dots + in-lane cells + early publish -------
    if (doA) {
      const float* ap = aring[(t - 1) & 7];
      float4 av[8];
#pragma unroll
      for (int j = 0; j < 8; j++) av[j] = ld4(ap + 4 * kc + 32 * j);
      float gv[4];
#pragma unroll
      for (int g = 0; g < 4; g++) {
        float4 s4 = {0, 0, 0, 0};
#pragma unroll
        for (int j = 0; j < 8; j++) {
          s4.x += wf0[g][j].x * av[j].x; s4.y += wf0[g][j].y * av[j].y;
          s4.z += wf0[g][j].z * av[j].z; s4.w += wf0[g][j].w * av[j].w;
        }
        float s = (s4.x + s4.y) + (s4.z + s4.w);
        s += __shfl_xor(s, 1); s += __shfl_xor(s, 2); s += __shfl_xor(s, 4);
        gv[g] = s + xa0s[g];
      }
      float ig = sigm_f(gv[0]);
      float fg = sigm_f(gv[1]);
      float cg = tanh_f(gv[2]);
      float og = sigm_f(gv[3]);
      cst0 = fg * cst0 + ig * cg;
      float a = og * tanh_f(cst0);
      if (kc == 0) {                       // 8 lanes/wave publish own cols
        u64 pk = ((u64)eA << 32) | (u64)__float_as_uint(a);
        AGST64(sexb + ((0 * 2 + pa) << 8) + col, pk);
        aring[t & 7][col] = a;             // own cols stay local
      }
    }
    if (doH) {
      const float* hp = hring[(t - 1) & 1];
      float4 hv[8];
#pragma unroll
      for (int j = 0; j < 8; j++) hv[j] = ld4(hp + 4 * kc + 32 * j);
      float gv[4];
#pragma unroll
      for (int g = 0; g < 4; g++) {
        float4 s4 = {0, 0, 0, 0};
#pragma unroll
        for (int j = 0; j < 8; j++) {
          s4.x += wf1[g][j].x * hv[j].x; s4.y += wf1[g][j].y * hv[j].y;
          s4.z += wf1[g][j].z * hv[j].z; s4.w += wf1[g][j].w * hv[j].w;
        }
        float s = (s4.x + s4.y) + (s4.z + s4.w);
        s += __shfl_xor(s, 1); s += __shfl_xor(s, 2); s += __shfl_xor(s, 4);
        gv[g] = s + xa1s[g];
      }
      float ig = sigm_f(gv[0]);
      float fg = sigm_f(gv[1]);
      float cg = tanh_f(gv[2]);
      float og = sigm_f(gv[3]);
      cst1 = fg * cst1 + ig * cg;
      float h = og * tanh_f(cst1);
      if (kc == 0) {
        outp[(size_t)u * H_ + col] = h;    // plain store for epilogue
        u64 pk = ((u64)eH << 32) | (u64)__float_as_uint(h);
        AGST64(sexb + ((1 * 2 + ph) << 8) + col, pk);
        hring[u & 1][col] = h;
      }
    }

    // ---- 3. off-critical-path work (overlaps publish propagation) ------
    // 3a. next xa0 from x_sh
    if (t + 1 < S_) {
      const float* xb = x_sh[(t + 1) & 1];
      float4 xv[4];
#pragma unroll
      for (int j = 0; j < 4; j++) xv[j] = ld4(xb + 4 * kc + 32 * j);
#pragma unroll
      for (int g = 0; g < 4; g++) {
        float4 s4 = {0, 0, 0, 0};
#pragma unroll
        for (int j = 0; j < 4; j++) {
          s4.x += wi0[g][j].x * xv[j].x; s4.y += wi0[g][j].y * xv[j].y;
          s4.z += wi0[g][j].z * xv[j].z; s4.w += wi0[g][j].w * xv[j].w;
        }
        float s = (s4.x + s4.y) + (s4.z + s4.w);
        s += __shfl_xor(s, 1); s += __shfl_xor(s, 2); s += __shfl_xor(s, 4);
        xa0s[g] = s + rb0[g];
      }
    }
    // 3b. xa1 for layer-1 step v = u+1: w1 (padded b128 stream) x aring[v]
    {
      const int v = t - D_ + 1;
      if (v >= 0 && v < S_) {
        const float* avp = aring[v & 7];
        float4 av[8];
#pragma unroll
        for (int j = 0; j < 8; j++) av[j] = ld4(avp + 4 * kc + 32 * j);
#pragma unroll
        for (int g = 0; g < 4; g++) {
          const float* wr = &w1[g * 32 + wrg][4 * kc];
          float4 s4 = {0, 0, 0, 0};
#pragma unroll
          for (int j = 0; j < 8; j++) {
            float4 wv = ld4(wr + 32 * j);
            s4.x += wv.x * av[j].x; s4.y += wv.y * av[j].y;
            s4.z += wv.z * av[j].z; s4.w += wv.w * av[j].w;
          }
          float s = (s4.x + s4.y) + (s4.z + s4.w);
          s += __shfl_xor(s, 1); s += __shfl_xor(s, 2); s += __shfl_xor(s, 4);
          xa1s[g] = s + rb1[g];
        }
      }
    }

    // ---- 4. gather: coalesced MALL pair-polls, proven atomic fallback ---
    {
      const bool isA = (tid < 128);
      const int  pi2 = isA ? tid : tid - 128;     // pair index 0..127
      const bool ownp = ((pi2 >> 4) == n);        // pair inside own 32 cols
      const bool act  = isA ? doA : doH;
      bool need = act && !ownp && !dead;
      if (need) {
        const unsigned etag = isA ? eA : eH;
        const int plane = isA ? (0 * 2 + pa) : (1 * 2 + ph);
        u64* base = sexb + (plane << 8) + 2 * pi2;
        unsigned val0 = 0, val1 = 0;
        bool got = false;
#pragma unroll 1
        for (int it = 0; it < 16 && !got; ++it) {
          u32x4 q = mall_load_2x64(base);
          if (q.y == etag && q.w == etag) { val0 = q.x; val1 = q.z; got = true; }
        }
        if (!got) {                               // proven coherent fallback
          bool g0 = false, g1 = false;
          unsigned guard = 0;
          while (!(g0 && g1)) {
            if (!g0) { u64 v = AGLD64(base);     if ((unsigned)(v >> 32) == etag) { val0 = (unsigned)v; g0 = true; } }
            if (!g1) { u64 v = AGLD64(base + 1); if ((unsigned)(v >> 32) == etag) { val1 = (unsigned)v; g1 = true; } }
            if (++guard >= (1u << 20)) { dead = true; break; }
          }
        }
        float2 f2;
        f2.x = __uint_as_float(val0);
        f2.y = __uint_as_float(val1);
        if (isA) *(float2*)&aring[t & 7][2 * pi2] = f2;
        else     *(float2*)&hring[u & 1][2 * pi2] = f2;
      }
    }

    if (tid < IN_ && t < S_) x_sh[t & 1][tid] = xreg;
    xreg = xreg_n;
    __syncthreads();
  }
}

// ---------------------------------------------------------------------------
// kNN memory read. One wave per token. enh = qw * enhanced  [MT,256] fp32.
// ---------------------------------------------------------------------------
__global__ __launch_bounds__(256) void knn_enh(
    const float* __restrict__ lstm, const float* __restrict__ Wcq,
    const float* __restrict__ bcq, const float* __restrict__ keys,
    const float* __restrict__ vals, const float* __restrict__ qwp,
    float* __restrict__ enh)
{
  const int tid  = threadIdx.x;
  const int wave = tid >> 6, lane = tid & 63;
  const int t = blockIdx.x * 4 + wave;

  __shared__ float xsh[4][256];
  __shared__ float qsh[4][16];

  const float* xrow = lstm + (size_t)t * H_;
  float4 x4 = ld4(xrow + lane * 4);
  *(float4*)&xsh[wave][lane * 4] = x4;
  __syncthreads();

  const int j = lane & 15, seg = lane >> 4;
  const float* wrow = Wcq + j * H_ + seg * 64;
  const float* xseg = &xsh[wave][seg * 64];
  float p = 0.0f;
#pragma unroll
  for (int c = 0; c < 64; c += 4) {
    float4 w4 = ld4(wrow + c);
    p += w4.x * xseg[c] + w4.y * xseg[c + 1] + w4.z * xseg[c + 2] + w4.w * xseg[c + 3];
  }
  p += __shfl_xor(p, 16);
  p += __shfl_xor(p, 32);
  float q = tanhf(p + bcq[j]);

  float sq = q * q;
  sq += __shfl_xor(sq, 1); sq += __shfl_xor(sq, 2);
  sq += __shfl_xor(sq, 4); sq += __shfl_xor(sq, 8);
  float qn = q / (sqrtf(sq) + 1e-8f);
  if (lane < 16) qsh[wave][lane] = qn;
  __syncthreads();

  const int m = lane;
  const float* krow = keys + m * Q_;
  float kv[16]; float kn2 = 0.0f;
#pragma unroll
  for (int jj = 0; jj < 16; jj++) { kv[jj] = krow[jj]; kn2 += kv[jj] * kv[jj]; }
  float rn = 1.0f / (sqrtf(kn2) + 1e-8f);
  float sim = 0.0f;
#pragma unroll
  for (int jj = 0; jj < 16; jj++) sim += qsh[wave][jj] * kv[jj];
  sim *= rn;

  float rem = sim;
  float tv[3]; int ti[3];
#pragma unroll
  for (int k = 0; k < 3; k++) {
    float v = rem; int idx = m;
#pragma unroll
    for (int d = 1; d < 64; d <<= 1) {
      float ov = __shfl_xor(v, d);
      int   oi = __shfl_xor(idx, d);
      if (ov > v || (ov == v && oi < idx)) { v = ov; idx = oi; }
    }
    tv[k] = v; ti[k] = idx;
    if (m == idx) rem = -INFINITY;
  }
  float tot = tv[0] + tv[1] + tv[2];

  float ex = 0, ey = 0, ez = 0, ew = 0;
#pragma unroll
  for (int k = 0; k < 3; k++) {
    float4 vv = ld4(vals + (size_t)ti[k] * H_ + lane * 4);
    ex += tv[k] * vv.x; ey += tv[k] * vv.y;
    ez += tv[k] * vv.z; ew += tv[k] * vv.w;
  }
  float inv = (tot > 0.0f) ? 1.0f / tot : 0.0f;
  const float qw = qwp[0];

  float4 o;
  o.x = qw * ex * inv; o.y = qw * ey * inv;
  o.z = qw * ez * inv; o.w = qw * ew * inv;
  *(float4*)&enh[(size_t)t * H_ + lane * 4] = o;
}

// ---------------------------------------------------------------------------
// Final projection, IN-PLACE on io (= d_out). Block owns 64 rows x all 256
// cols; reads its own rows, writes after the K-loop -> race-free in-place.
// ---------------------------------------------------------------------------
__global__ __launch_bounds__(256) void gemm_cat(
    float* __restrict__ io, const float* __restrict__ A2,
    const float* __restrict__ Bw, const float* __restrict__ bias,
    const float* __restrict__ cwp)
{
  __shared__ float As[16][68];
  __shared__ float Bs[16][260];
  const int tid  = threadIdx.x;
  const int row0 = blockIdx.x * 64;
  const int tx = tid & 15, ty = tid >> 4;
  const int lr = tid >> 2;
  const int lk = (tid & 3) << 2;
  const float cw = cwp[0];

  float acc[4][16];
#pragma unroll
  for (int i = 0; i < 4; i++)
#pragma unroll
    for (int j = 0; j < 16; j++) acc[i][j] = 0.0f;

  for (int k0 = 0; k0 < 512; k0 += 16) {
    float4 av;
    if (k0 < 256) {
      av = ld4(io + (size_t)(row0 + lr) * 256 + k0 + lk);
      av.x *= cw; av.y *= cw; av.z *= cw; av.w *= cw;
    } else {
      av = ld4(A2 + (size_t)(row0 + lr) * 256 + (k0 - 256) + lk);
    }
    As[lk + 0][lr] = av.x; As[lk + 1][lr] = av.y;
    As[lk + 2][lr] = av.z; As[lk + 3][lr] = av.w;
    const float* bp = Bw + (size_t)tid * 512 + k0;
#pragma unroll
    for (int q = 0; q < 4; q++) {
      float4 b4 = ld4(bp + 4 * q);
      Bs[4 * q + 0][tid] = b4.x; Bs[4 * q + 1][tid] = b4.y;
      Bs[4 * q + 2][tid] = b4.z; Bs[4 * q + 3][tid] = b4.w;
    }
    __syncthreads();
#pragma unroll
    for (int k = 0; k < 16; k++) {
      float4 a4 = *(const float4*)&As[k][ty << 2];
      float aa[4] = {a4.x, a4.y, a4.z, a4.w};
#pragma unroll
      for (int cc = 0; cc < 4; cc++) {
        float4 b4 = *(const float4*)&Bs[k][cc * 64 + (tx << 2)];
        float bb[4] = {b4.x, b4.y, b4.z, b4.w};
#pragma unroll
        for (int i = 0; i < 4; i++)
#pragma unroll
          for (int jj = 0; jj < 4; jj++) acc[i][cc * 4 + jj] += aa[i] * bb[jj];
      }
    }
    __syncthreads();
  }

#pragma unroll
  for (int i = 0; i < 4; i++) {
#pragma unroll
    for (int cc = 0; cc < 4; cc++) {
      int c0 = cc * 64 + (tx << 2);
      float4 o;
      o.x = acc[i][cc * 4 + 0] + bias[c0 + 0];
      o.y = acc[i][cc * 4 + 1] + bias[c0 + 1];
      o.z = acc[i][cc * 4 + 2] + bias[c0 + 2];
      o.w = acc[i][cc * 4 + 3] + bias[c0 + 3];
      *(float4*)&io[(size_t)(row0 + (ty << 2) + i) * 256 + c0] = o;
    }
  }
}

// ---------------------------------------------------------------------------
extern "C" void kernel_launch(void* const* d_in, const int* in_sizes, int n_in,
                              void* d_out, int out_size, void* d_ws, size_t ws_size,
                              hipStream_t stream)
{
  const float* x    = (const float*)d_in[0];
  const float* Wih0 = (const float*)d_in[1];
  const float* Whh0 = (const float*)d_in[2];
  const float* bih0 = (const float*)d_in[3];
  const float* bhh0 = (const float*)d_in[4];
  const float* Wih1 = (const float*)d_in[5];
  const float* Whh1 = (const float*)d_in[6];
  const float* bih1 = (const float*)d_in[7];
  const float* bhh1 = (const float*)d_in[8];
  const float* Wcq  = (const float*)d_in[9];
  const float* bcq  = (const float*)d_in[10];
  const float* keys = (const float*)d_in[11];
  const float* vals = (const float*)d_in[12];
  const float* Wout = (const float*)d_in[13];
  const float* bout = (const float*)d_in[14];
  const float* cw   = (const float*)d_in[15];
  const float* qw   = (const float*)d_in[16];
  float* out = (float*)d_out;

  // ws: [exchange 256 KB (dead after lstm2)] overlapped with enh [MT,256] f32.
  const size_t HE = (size_t)B_ * S_ * H_;
  if (ws_size < HE * sizeof(float)) return;   // 67.1 MB (round-4 proven OK)
  u64* exs = (u64*)d_ws;
  float* enh = (float*)d_ws;

  const int MT = B_ * S_;
  dim3 blk(256);

  hipMemsetAsync(exs, 0, (size_t)32 * 1024 * sizeof(u64), stream);
  lstm2<<<dim3(256), blk, 0, stream>>>(x, Wih0, bih0, bhh0, Whh0,
                                       Wih1, bih1, bhh1, Whh1, out, exs);

  knn_enh<<<dim3(MT / 4), blk, 0, stream>>>(out, Wcq, bcq, keys, vals, qw, enh);

  gemm_cat<<<dim3(MT / 64), blk, 0, stream>>>(out, enh, Wout, bout, cw);
}